// Round 12
// baseline (232.813 us; speedup 1.0000x reference)
//
#include <hip/hip_runtime.h>
#include <hip/hip_bf16.h>

// Longformer self-attention, MI355X gfx950 — ROUND 24.
// fp32 I/O, f16 intermediates. Changes vs R23 (qkv only; band_global/prep/
// reduce byte-identical proven code):
//  qkv_mfma12 — faithful multi-phase port (guide §5.5 T3+T4 regime):
//   * BM=BN=256, BK=32, 512 thr (8 waves 2Mx4N), per-wave 128x64, acc[8][4].
//   * 4 LDS slots x 32KB (A16+B16) = 128KB; stage lead 3 tiles.
//   * 2 phases/K-tile (m-half): {vmcnt(8)[ph0] -> s_barrier -> sched_barrier
//     -> stage 2 gl_lds of tile t+3 (A in ph0, B in ph1) -> ds_read frags ->
//     setprio(1) -> 16 MFMA -> setprio(0)}. Loads NEVER drain below 8
//     outstanding in steady state (audit: at (t,0) tile t's 4 loads retire,
//     tiles t+1,t+2 = 8 stay in flight; tail 8/4/0). 48 phase-barriers.
//   * bf frags hoisted across the phase pair: 12 ds_read_b128 / tile.
//   * proven swizzle family: pre-swizzled GLOBAL source (rule 21), linear
//     LDS dest (gl_lds lane-contiguous), XOR on read. cg=(l&3)^((l>>3)&3).
//   * two-pass epilogue (M-halves) reusing LDS as Cl; XCD remap (4 mt/XCD).
//  Rationale: R12-R19 were 1-phase-per-tile; regime-gate (m218/m196/m230)
//  says counted-vmcnt/T5 pay ONLY inside a fine multi-phase schedule.
//  2x arithmetic intensity vs R19 (576 blocks re-read A,B half as often).

#define DEVI __device__ __forceinline__
typedef _Float16 f16;
typedef _Float16 h4 __attribute__((ext_vector_type(4)));
typedef _Float16 f16x8 __attribute__((ext_vector_type(8)));
typedef __attribute__((ext_vector_type(4))) float float4v;

DEVI float4v mfma16(f16x8 a, f16x8 b, float4v c) {
    return __builtin_amdgcn_mfma_f32_16x16x32_f16(a, b, c, 0, 0, 0);
}

DEVI void gl_lds16(const f16* g, f16* l) {
    __builtin_amdgcn_global_load_lds(
        (const __attribute__((address_space(1))) unsigned int*)g,
        (__attribute__((address_space(3))) unsigned int*)l, 16, 0, 0);
}

// ---------------------------------------------------------------------------
// prep: blocks [0,6144) = xcast (fp32->f16, 8192*768); blocks [6144,7008) =
// weight transpose Wt[i*768+n][k] = (f16) W_i[k][n].
// ---------------------------------------------------------------------------
__global__ __launch_bounds__(256) void prep(
    const float* __restrict__ x,
    const float* __restrict__ w0, const float* __restrict__ w1,
    const float* __restrict__ w2, const float* __restrict__ w3,
    const float* __restrict__ w4, const float* __restrict__ w5,
    f16* __restrict__ xh, f16* __restrict__ wt) {
    __shared__ float tile[64][65];
    int bid = blockIdx.x;
    if (bid < 6144) {
        int i = (bid * 256 + threadIdx.x) * 4;
        float4 v = *(const float4*)&x[i];
        h4 o = {(f16)v.x, (f16)v.y, (f16)v.z, (f16)v.w};
        *(h4*)&xh[i] = o;
    } else {
        int t = bid - 6144;
        int i = t / 144, rem = t - i * 144;
        int n0 = (rem % 12) * 64, k0 = (rem / 12) * 64;
        const float* W = (i == 0) ? w0 : (i == 1) ? w1 : (i == 2) ? w2
                       : (i == 3) ? w3 : (i == 4) ? w4 : w5;
        int tx = threadIdx.x & 63, ty = threadIdx.x >> 6;
#pragma unroll
        for (int yy = 0; yy < 64; yy += 4)
            tile[yy + ty][tx] = W[(size_t)(k0 + yy + ty) * 768 + n0 + tx];
        __syncthreads();
#pragma unroll
        for (int yy = 0; yy < 64; yy += 4)
            wt[(size_t)(i * 768 + n0 + yy + ty) * 768 + k0 + tx] = (f16)tile[tx][yy + ty];
    }
}

// ---------------------------------------------------------------------------
// qkv_mfma12: 256x256 tile, 8 waves, 2-phase-per-K-tile counted pipeline.
// ---------------------------------------------------------------------------
__global__ __launch_bounds__(512, 2) void qkv_mfma12(
    const f16* __restrict__ Xh, const f16* __restrict__ Wt,
    const float* __restrict__ b0, const float* __restrict__ b1,
    const float* __restrict__ b2, const float* __restrict__ b3,
    const float* __restrict__ b4, const float* __restrict__ b5,
    f16* __restrict__ q, f16* __restrict__ k, f16* __restrict__ vT,
    f16* __restrict__ qg, f16* __restrict__ kg, f16* __restrict__ vgT) {
    __shared__ __align__(16) char smem[131072];   // 4 slots x (16KB A + 16KB B)
    f16* smemf = (f16*)smem;
    f16* Cl = smemf;                              // aliased epilogue buffer

    int tid = threadIdx.x, lane = tid & 63, wid = tid >> 6;
    int quad = lane >> 4, l15 = lane & 15;
    int wr = wid >> 2, wc = wid & 3;              // wave grid 2(M) x 4(N)
    int wrb = wr * 128, wcb = wc * 64;

    // XCD remap (bijective): 576 blocks; xcd=L&7 owns m-tiles xcd*4..+3
    // across all 18 y (y slowest within XCD).
    int L = blockIdx.x;
    int xcd = L & 7, W = L >> 3;                  // W in 0..71
    int mt = xcd * 4 + (W & 3);                   // 0..31
    int yy = W >> 2;                              // 0..17
    int m0 = mt * 256;
    int grp = yy / 3;
    if (grp == 3 && (m0 & 4095) != 0) return;     // qg: only s<32 tiles matter
    int nb = (yy - grp * 3) * 256;                // 0 / 256 / 512
    const f16* arow0 = Xh + (size_t)m0 * 768;
    const f16* brow0 = Wt + (size_t)(grp * 768 + nb) * 768;

    float4v acc[8][4];
#pragma unroll
    for (int i = 0; i < 8; ++i)
#pragma unroll
        for (int j = 0; j < 4; ++j) acc[i][j] = (float4v){0.f, 0.f, 0.f, 0.f};

    // Staging: gl_lds writes lane l at base + l*16B (wave-uniform base).
    // One instruction covers 16 rows x 64B. Wave w, load i: rows
    // [w*32+i*16, +16); lane l -> row w*32+i*16+(l>>2), lds chunk l&3.
    // Pre-swizzled GLOBAL chunk cg = (l&3)^((row>>1)&3) = (l&3)^((l>>3)&3)
    // (w*32+i*16 is 0 mod 8). Read side: chunk quad^((l15>>1)&3).
    int cgl = (((lane & 3) ^ ((lane >> 3) & 3)) << 3);   // f16 units
    int sw8 = ((quad ^ ((l15 >> 1) & 3)) << 3);

    auto Aslot = [&](int s) { return smemf + s * 16384; };
    auto Bslot = [&](int s) { return smemf + s * 16384 + 8192; };
    auto STAGE_A = [&](int kt, int s) {
        int k0 = kt << 5;
        const f16* g = arow0 + (size_t)(wid * 32 + (lane >> 2)) * 768 + k0 + cgl;
        f16* l0 = Aslot(s) + (wid * 32) * 32;
        gl_lds16(g, l0);
        gl_lds16(g + (size_t)16 * 768, l0 + 512);
    };
    auto STAGE_B = [&](int kt, int s) {
        int k0 = kt << 5;
        const f16* g = brow0 + (size_t)(wid * 32 + (lane >> 2)) * 768 + k0 + cgl;
        f16* l0 = Bslot(s) + (wid * 32) * 32;
        gl_lds16(g, l0);
        gl_lds16(g + (size_t)16 * 768, l0 + 512);
    };

    // Pipeline audit (per-thread issue order A(u),A(u),B(u),B(u) per tile):
    //  - tile u staged during Q_{u-3} (A in ph0, B in ph1) into slot u&3 =
    //    (u-4)&3... slot u&3 was last READ at tile u-4, finished before the
    //    (u-3,0) barrier; stage issues after it. Safe.
    //  - at (t,0): vmcnt(8) retires tile t's 4 loads exactly; tiles t+1,t+2
    //    (8 loads) stay in flight ACROSS the barrier. Tail: t=22 ->4, 23 ->0.
    STAGE_A(0, 0); STAGE_B(0, 0);
    STAGE_A(1, 1); STAGE_B(1, 1);
    STAGE_A(2, 2); STAGE_B(2, 2);
#pragma unroll
    for (int t = 0; t < 24; ++t) {
        // ---- phase 0 (m-frags 0..3) ----
        if (t < 22)       asm volatile("s_waitcnt vmcnt(8)" ::: "memory");
        else if (t == 22) asm volatile("s_waitcnt vmcnt(4)" ::: "memory");
        else              asm volatile("s_waitcnt vmcnt(0)" ::: "memory");
        __builtin_amdgcn_s_barrier();
        __builtin_amdgcn_sched_barrier(0);
        if (t + 3 <= 23) STAGE_A(t + 3, (t + 3) & 3);
        const f16* Ab = Aslot(t & 3);
        const f16* Bb = Bslot(t & 3);
        f16x8 bf[4];
#pragma unroll
        for (int j = 0; j < 4; ++j)
            bf[j] = *(const f16x8*)&Bb[(wcb + j * 16 + l15) * 32 + sw8];
        {
            f16x8 af[4];
#pragma unroll
            for (int i = 0; i < 4; ++i)
                af[i] = *(const f16x8*)&Ab[(wrb + i * 16 + l15) * 32 + sw8];
            __builtin_amdgcn_s_setprio(1);
#pragma unroll
            for (int i = 0; i < 4; ++i)
#pragma unroll
                for (int j = 0; j < 4; ++j)
                    acc[i][j] = mfma16(af[i], bf[j], acc[i][j]);
            __builtin_amdgcn_s_setprio(0);
        }
        // ---- phase 1 (m-frags 4..7) ----
        __builtin_amdgcn_s_barrier();
        __builtin_amdgcn_sched_barrier(0);
        if (t + 3 <= 23) STAGE_B(t + 3, (t + 3) & 3);
        {
            f16x8 af[4];
#pragma unroll
            for (int i = 0; i < 4; ++i)
                af[i] = *(const f16x8*)&Ab[(wrb + 64 + i * 16 + l15) * 32 + sw8];
            __builtin_amdgcn_s_setprio(1);
#pragma unroll
            for (int i = 0; i < 4; ++i)
#pragma unroll
                for (int j = 0; j < 4; ++j)
                    acc[4 + i][j] = mfma16(af[i], bf[j], acc[4 + i][j]);
            __builtin_amdgcn_s_setprio(0);
        }
    }
    __syncthreads();   // drain; slots reusable as Cl

    const float* Bsel = (grp == 0) ? b0 : (grp == 1) ? b1 : (grp == 2) ? b2
                      : (grp == 3) ? b3 : (grp == 4) ? b4 : b5;
    int b = m0 >> 12;
    bool tr = (grp == 2 || grp == 5);

    if (tr) {
        constexpr int CLD2 = 136;                 // 256*136*2 = 69632 B
#pragma unroll
        for (int ph = 0; ph < 2; ++ph) {
            if (wr == ph) {
#pragma unroll
                for (int j = 0; j < 4; ++j) {
                    float bias = Bsel[nb + wcb + j * 16 + l15];
#pragma unroll
                    for (int i = 0; i < 8; ++i) {
                        float4v a = acc[i][j];
                        h4 pk = {(f16)(a[0] + bias), (f16)(a[1] + bias),
                                 (f16)(a[2] + bias), (f16)(a[3] + bias)};
                        *(h4*)&Cl[(wcb + j * 16 + l15) * CLD2 + i * 16 + quad * 4] = pk;
                    }
                }
            }
            __syncthreads();
            {
                f16* base = (grp == 2) ? vT : vgT;
                int c = tid >> 1, rh = tid & 1;
                int ncol = nb + c, hh = ncol >> 6, hd = ncol & 63;
                f16* dst = &base[((size_t)((b * 12 + hh) * 64 + hd)) * 4096 +
                                 (m0 & 4095) + ph * 128 + rh * 64];
                const f16* src = &Cl[c * CLD2 + rh * 64];
#pragma unroll
                for (int ii = 0; ii < 8; ++ii)
                    *(f16x8*)&dst[ii * 8] = *(const f16x8*)&src[ii * 8];
            }
            __syncthreads();
        }
    } else {
        constexpr int CLD = 264;                  // 128*264*2 = 67584 B
        float scale = (grp == 0 || grp == 3) ? 0.125f : 1.0f;
#pragma unroll
        for (int ph = 0; ph < 2; ++ph) {
            if (wr == ph) {
#pragma unroll
                for (int j = 0; j < 4; ++j) {
                    float bias = Bsel[nb + wcb + j * 16 + l15];
#pragma unroll
                    for (int i = 0; i < 8; ++i) {
                        float4v a = acc[i][j];
#pragma unroll
                        for (int r = 0; r < 4; ++r)
                            Cl[(i * 16 + quad * 4 + r) * CLD + wcb + j * 16 + l15] =
                                (f16)((a[r] + bias) * scale);
                    }
                }
            }
            __syncthreads();
            {
                int row = tid & 127, qtr = tid >> 7;
                int s = (m0 & 4095) + ph * 128 + row;
                int hh = (nb + qtr * 64) >> 6;
                const f16* src = &Cl[row * CLD + qtr * 64];
                if (grp == 3) {
                    if (s < 32) {
                        f16* dst = &qg[((size_t)((b * 12 + hh) * 32 + s)) * 64];
#pragma unroll
                        for (int ii = 0; ii < 8; ++ii)
                            *(f16x8*)&dst[ii * 8] = *(const f16x8*)&src[ii * 8];
                    }
                } else {
                    f16* baseb = (grp == 0) ? q : (grp == 1) ? k : kg;
                    f16* dst = &baseb[((size_t)((b * 12 + hh) * 4096 + s)) * 64];
#pragma unroll
                    for (int ii = 0; ii < 8; ++ii)
                        *(f16x8*)&dst[ii * 8] = *(const f16x8*)&src[ii * 8];
                }
            }
            __syncthreads();
        }
    }
}

// ---------------------------------------------------------------------------
// band_global: blocks [0,768) = band_mfma5 body (R11 mapping, proven);
// blocks [768,960) = global_part body (proven). LDS unioned: 51712 B
// (band 46080, gp 51712) -> 3 blocks/CU.
// ---------------------------------------------------------------------------
__global__ __launch_bounds__(256, 3) void band_global(
    const f16* __restrict__ q, const f16* __restrict__ k, const f16* __restrict__ vT,
    const f16* __restrict__ qg, const f16* __restrict__ kg, const f16* __restrict__ vgT,
    float* __restrict__ out, float* __restrict__ Opart, float* __restrict__ Lpart) {
    __shared__ __align__(16) char smem[51712];
    int tid = threadIdx.x, lane = tid & 63, wid = tid >> 6;
    int quad = lane >> 4, l15 = lane & 15;

    if (blockIdx.x < 768) {
        // ----- band body (R11 proven, linear c mapping) -----
        constexpr int LDK = 72, LDV = 136, LDP = 40;
        f16* Kt = (f16*)smem;                          // 128*72*2   = 18432
        f16* Vt = (f16*)(smem + 18432);                // 64*136*2   = 17408
        f16* PW = (f16*)(smem + 35840) + wid * 32 * LDP;  // 4*32*40*2 = 10240
        int c = blockIdx.x & 31, h = (blockIdx.x >> 5) % 12, b = blockIdx.x / 384;
        const f16* qsl = q + (size_t)(b * 12 + h) * 4096 * 64;
        const f16* ksl = k + (size_t)(b * 12 + h) * 4096 * 64;
        const f16* vsl = vT + (size_t)(b * 12 + h) * 64 * 4096;
        int q0 = c * 128;
        int pq0 = q0 + wid * 32;

        f16x8 qf[2][2];
#pragma unroll
        for (int qg2 = 0; qg2 < 2; ++qg2)
#pragma unroll
            for (int ks = 0; ks < 2; ++ks)
                qf[qg2][ks] = *(const f16x8*)&qsl[(size_t)(pq0 + qg2 * 16 + l15) * 64 +
                                                  ks * 32 + quad * 8];

        float4v Ot[4][2];
#pragma unroll
        for (int dt = 0; dt < 4; ++dt)
#pragma unroll
            for (int qg2 = 0; qg2 < 2; ++qg2) Ot[dt][qg2] = (float4v){0.f, 0.f, 0.f, 0.f};
        float lacc[2] = {0.f, 0.f};

        {
#pragma unroll
            for (int jt = 0; jt < 2; ++jt) {
                f16x8 kf0 = *(const f16x8*)&ksl[(size_t)(jt * 16 + l15) * 64 + quad * 8];
                f16x8 kf1 = *(const f16x8*)&ksl[(size_t)(jt * 16 + l15) * 64 + 32 + quad * 8];
#pragma unroll
                for (int qg2 = 0; qg2 < 2; ++qg2) {
                    float4v sacc = (float4v){0.f, 0.f, 0.f, 0.f};
                    sacc = mfma16(kf0, qf[qg2][0], sacc);
                    sacc = mfma16(kf1, qf[qg2][1], sacc);
                    float p0 = __expf(sacc[0]), p1 = __expf(sacc[1]);
                    float p2 = __expf(sacc[2]), p3 = __expf(sacc[3]);
                    lacc[qg2] += (p0 + p1) + (p2 + p3);
                    h4 pk = {(f16)p0, (f16)p1, (f16)p2, (f16)p3};
                    *(h4*)&PW[(qg2 * 16 + l15) * LDP + jt * 16 + quad * 4] = pk;
                }
            }
            f16x8 pf0 = *(const f16x8*)&PW[l15 * LDP + quad * 8];
            f16x8 pf1 = *(const f16x8*)&PW[(16 + l15) * LDP + quad * 8];
#pragma unroll
            for (int dt = 0; dt < 4; ++dt) {
                f16x8 vf = *(const f16x8*)&vsl[(size_t)(dt * 16 + l15) * 4096 + quad * 8];
                Ot[dt][0] = mfma16(vf, pf0, Ot[dt][0]);
                Ot[dt][1] = mfma16(vf, pf1, Ot[dt][1]);
            }
        }

        for (int r = 0; r < 5; ++r) {
            int kb = q0 - 256 + r * 128;
            if (kb < 0 || kb >= 4096) continue;
            __syncthreads();
            {
                int kr = tid >> 1, ko = (tid & 1) * 32;
                const f16* ks2 = &ksl[(size_t)(kb + kr) * 64 + ko];
                f16* kd = &Kt[kr * LDK + ko];
#pragma unroll
                for (int i = 0; i < 4; ++i) *(f16x8*)&kd[i * 8] = *(const f16x8*)&ks2[i * 8];
                int vr = tid >> 2, vo = (tid & 3) * 32;
                const f16* vs2 = &vsl[(size_t)vr * 4096 + kb + vo];
                f16* vd = &Vt[vr * LDV + vo];
#pragma unroll
                for (int i = 0; i < 4; ++i) *(f16x8*)&vd[i * 8] = *(const f16x8*)&vs2[i * 8];
            }
            __syncthreads();

            if (kb + 127 < pq0 - 256 || kb > pq0 + 287) continue;

#pragma unroll
            for (int tt = 0; tt < 2; ++tt) {
                int tb = kb + tt * 64;
                if (tb + 63 < pq0 - 256 || tb > pq0 + 287) continue;
#pragma unroll
                for (int hf = 0; hf < 2; ++hf) {
#pragma unroll
                    for (int jt = 0; jt < 2; ++jt) {
                        int jl = tt * 64 + hf * 32 + jt * 16;
                        f16x8 kf0 = *(const f16x8*)&Kt[(jl + l15) * LDK + quad * 8];
                        f16x8 kf1 = *(const f16x8*)&Kt[(jl + l15) * LDK + 32 + quad * 8];
                        int j0 = kb + jl;
#pragma unroll
                        for (int qg2 = 0; qg2 < 2; ++qg2) {
                            int qlo = pq0 + qg2 * 16;
                            h4 pk = {(f16)0.f, (f16)0.f, (f16)0.f, (f16)0.f};
                            bool dead = (j0 < qlo - 271) || (j0 > qlo + 271);
                            if (!dead) {
                                float4v sacc = (float4v){0.f, 0.f, 0.f, 0.f};
                                sacc = mfma16(kf0, qf[qg2][0], sacc);
                                sacc = mfma16(kf1, qf[qg2][1], sacc);
                                float p[4];
                                bool full = (j0 >= qlo - 241) && (j0 <= qlo + 241);
                                if (full) {
#pragma unroll
                                    for (int rr = 0; rr < 4; ++rr) p[rr] = __expf(sacc[rr]);
                                } else {
#pragma unroll
                                    for (int rr = 0; rr < 4; ++rr) {
                                        int d = (j0 + quad * 4 + rr) - (qlo + l15);
                                        p[rr] = ((unsigned)(d + 256) <= 512u) ? __expf(sacc[rr]) : 0.f;
                                    }
                                }
                                lacc[qg2] += (p[0] + p[1]) + (p[2] + p[3]);
                                pk = (h4){(f16)p[0], (f16)p[1], (f16)p[2], (f16)p[3]};
                            }
                            *(h4*)&PW[(qg2 * 16 + l15) * LDP + jt * 16 + quad * 4] = pk;
                        }
                    }
                    f16x8 pf0 = *(const f16x8*)&PW[l15 * LDP + quad * 8];
                    f16x8 pf1 = *(const f16x8*)&PW[(16 + l15) * LDP + quad * 8];
#pragma unroll
                    for (int dt = 0; dt < 4; ++dt) {
                        f16x8 vf = *(const f16x8*)&Vt[(dt * 16 + l15) * LDV +
                                                      tt * 64 + hf * 32 + quad * 8];
                        Ot[dt][0] = mfma16(vf, pf0, Ot[dt][0]);
                        Ot[dt][1] = mfma16(vf, pf1, Ot[dt][1]);
                    }
                }
            }
        }

#pragma unroll
        for (int qg2 = 0; qg2 < 2; ++qg2) {
            float lsum = lacc[qg2];
            lsum += __shfl_xor(lsum, 16);
            lsum += __shfl_xor(lsum, 32);
            float inv = 1.f / lsum;
            size_t orow = (size_t)(b * 4096 + pq0 + qg2 * 16 + l15) * 768 + h * 64;
#pragma unroll
            for (int dt = 0; dt < 4; ++dt) {
                float4 o4 = {Ot[dt][qg2][0] * inv, Ot[dt][qg2][1] * inv,
                             Ot[dt][qg2][2] * inv, Ot[dt][qg2][3] * inv};
                *(float4*)&out[orow + dt * 16 + quad * 4] = o4;
            }
        }
    } else {
        // ----- global_part body (proven) -----
        constexpr int LDP = 72;
        f16* PW = (f16*)smem + wid * 32 * LDP;         // 4*32*72*2 = 18432
        float* Osh = (float*)(smem + 18432);           // 4*2048*4  = 32768
        float* Lsh = (float*)(smem + 18432 + 32768);   // 4*32*4    = 512
        int bid = blockIdx.x - 768;
        int sl = bid & 7, bh = bid >> 3;
        const f16* qsl = qg + (size_t)bh * 32 * 64;
        const f16* ksl = kg + (size_t)bh * 4096 * 64;
        const f16* vsl = vgT + (size_t)bh * 64 * 4096;
        int kbase = sl * 512 + wid * 128;

        f16x8 qf[2][2];
#pragma unroll
        for (int g = 0; g < 2; ++g)
#pragma unroll
            for (int ks = 0; ks < 2; ++ks)
                qf[g][ks] = *(const f16x8*)&qsl[(size_t)(g * 16 + l15) * 64 + ks * 32 + quad * 8];

        float4v Ot[4][2];
#pragma unroll
        for (int dt = 0; dt < 4; ++dt)
#pragma unroll
            for (int g = 0; g < 2; ++g) Ot[dt][g] = (float4v){0.f, 0.f, 0.f, 0.f};
        float lacc[2] = {0.f, 0.f};

#pragma unroll
        for (int hf = 0; hf < 2; ++hf) {
            int kh0 = kbase + hf * 64;
#pragma unroll
            for (int kt = 0; kt < 4; ++kt) {
                int jb = kh0 + kt * 16;
                f16x8 kf0 = *(const f16x8*)&ksl[(size_t)(jb + l15) * 64 + quad * 8];
                f16x8 kf1 = *(const f16x8*)&ksl[(size_t)(jb + l15) * 64 + 32 + quad * 8];
#pragma unroll
                for (int g = 0; g < 2; ++g) {
                    float4v sacc = (float4v){0.f, 0.f, 0.f, 0.f};
                    sacc = mfma16(kf0, qf[g][0], sacc);
                    sacc = mfma16(kf1, qf[g][1], sacc);
                    float p0 = __expf(sacc[0]), p1 = __expf(sacc[1]);
                    float p2 = __expf(sacc[2]), p3 = __expf(sacc[3]);
                    lacc[g] += (p0 + p1) + (p2 + p3);
                    h4 pk = {(f16)p0, (f16)p1, (f16)p2, (f16)p3};
                    *(h4*)&PW[(g * 16 + l15) * LDP + kt * 16 + quad * 4] = pk;
                }
            }
#pragma unroll
            for (int kh = 0; kh < 2; ++kh) {
                f16x8 pf0 = *(const f16x8*)&PW[l15 * LDP + kh * 32 + quad * 8];
                f16x8 pf1 = *(const f16x8*)&PW[(16 + l15) * LDP + kh * 32 + quad * 8];
#pragma unroll
                for (int dt = 0; dt < 4; ++dt) {
                    f16x8 vf = *(const f16x8*)&vsl[(size_t)(dt * 16 + l15) * 4096 +
                                                   kh0 + kh * 32 + quad * 8];
                    Ot[dt][0] = mfma16(vf, pf0, Ot[dt][0]);
                    Ot[dt][1] = mfma16(vf, pf1, Ot[dt][1]);
                }
            }
        }

#pragma unroll
        for (int g = 0; g < 2; ++g) {
            lacc[g] += __shfl_xor(lacc[g], 16);
            lacc[g] += __shfl_xor(lacc[g], 32);
        }
        if (quad == 0) { Lsh[wid * 32 + l15] = lacc[0]; Lsh[wid * 32 + 16 + l15] = lacc[1]; }
#pragma unroll
        for (int dt = 0; dt < 4; ++dt)
#pragma unroll
            for (int g = 0; g < 2; ++g)
#pragma unroll
                for (int r = 0; r < 4; ++r)
                    Osh[wid * 2048 + (dt * 16 + quad * 4 + r) * 32 + g * 16 + l15] = Ot[dt][g][r];
        __syncthreads();
#pragma unroll
        for (int i = 0; i < 8; ++i) {
            int idx = tid + i * 256;
            int d = idx & 63, qq = idx >> 6;
            float v = Osh[0 * 2048 + d * 32 + qq] + Osh[1 * 2048 + d * 32 + qq] +
                      Osh[2 * 2048 + d * 32 + qq] + Osh[3 * 2048 + d * 32 + qq];
            Opart[(size_t)bid * 2048 + idx] = v;
        }
        if (tid < 32)
            Lpart[bid * 32 + tid] = Lsh[0 * 32 + tid] + Lsh[1 * 32 + tid] +
                                    Lsh[2 * 32 + tid] + Lsh[3 * 32 + tid];
    }
}

__global__ __launch_bounds__(256) void global_reduce(
    const float* __restrict__ Opart, const float* __restrict__ Lpart,
    float* __restrict__ out) {
    __shared__ float Ls[32];
    int tid = threadIdx.x, bh = blockIdx.x;
    int b = bh / 12, h = bh % 12;
    if (tid < 32) {
        float s = 0.f;
#pragma unroll
        for (int sl = 0; sl < 8; ++sl) s += Lpart[(bh * 8 + sl) * 32 + tid];
        Ls[tid] = s;
    }
    __syncthreads();
#pragma unroll
    for (int i = 0; i < 8; ++i) {
        int idx = tid + i * 256;
        int d = idx & 63, qq = idx >> 6;
        float o = 0.f;
#pragma unroll
        for (int sl = 0; sl < 8; ++sl) o += Opart[(size_t)(bh * 8 + sl) * 2048 + idx];
        out[(size_t)(b * 4096 + qq) * 768 + h * 64 + d] = o / Ls[qq];
    }
}

// ---------------------------------------------------------------------------
extern "C" void kernel_launch(void* const* d_in, const int* in_sizes, int n_in,
                              void* d_out, int out_size, void* d_ws, size_t ws_size,
                              hipStream_t stream) {
    const float* hs = (const float*)d_in[0];
    float* outp = (float*)d_out;

    char* p = (char*)d_ws;
    const size_t SLAB = (size_t)2 * 12 * 4096 * 64 * sizeof(f16);   // 12,582,912 B
    f16* qb   = (f16*)(p + 0 * SLAB);
    f16* kb   = (f16*)(p + 1 * SLAB);
    f16* vtb  = (f16*)(p + 2 * SLAB);   // [bh][d][s]
    f16* kgb  = (f16*)(p + 3 * SLAB);
    f16* vgtb = (f16*)(p + 4 * SLAB);   // [bh][d][s]
    f16* qgb  = (f16*)(p + 5 * SLAB);
    char* p2  = p + 5 * SLAB + 196608;
    f16* xh   = (f16*)p2;
    f16* wt   = (f16*)(p2 + SLAB);
    char* p3  = p2 + SLAB + 7077888;
    float* Opart = (float*)p3;
    float* Lpart = (float*)(p3 + 1572864);

    prep<<<7008, 256, 0, stream>>>(
        hs,
        (const float*)d_in[1], (const float*)d_in[3], (const float*)d_in[5],
        (const float*)d_in[7], (const float*)d_in[9], (const float*)d_in[11],
        xh, wt);
    qkv_mfma12<<<576, 512, 0, stream>>>(
        xh, wt,
        (const float*)d_in[2], (const float*)d_in[4], (const float*)d_in[6],
        (const float*)d_in[8], (const float*)d_in[10], (const float*)d_in[12],
        qb, kb, vtb, qgb, kgb, vgtb);
    band_global<<<960, 256, 0, stream>>>(
        qb, kb, vtb, qgb, kgb, vgtb, outp, Opart, Lpart);
    global_reduce<<<24, 256, 0, stream>>>(Opart, Lpart, outp);
}

// Round 13
// 218.141 us; speedup vs baseline: 1.0673x; 1.0673x over previous
//
#include <hip/hip_runtime.h>
#include <hip/hip_bf16.h>

// Longformer self-attention, MI355X gfx950 — ROUND 25 (final; = R23/R21 exact).
// R24's fine-2-phase 256^2 port regressed qkv 80->87.5us (2nd refutation of
// the 256^2 family after R15: at K=768/24-tiles, qkv is latency x occupancy
// bound; deep pipelines never amortize). Locking in the best-verified
// artifact: R23 = 218.2us.
//
// Final composition:
//  - qkv_mfma11: 128x256 tile, 64x128 wave tile, ring-3 counted vmcnt,
//    XCD remap (FETCH 45->36MB), XOR swizzle (conflicts 6.1M->197K),
//    setprio. ~80us.
//  - band_global: band (R11 linear-c) blocks [0,768) + global_part blocks
//    [768,960); LDS union 51712B -> 3 blocks/CU. <77us (never in top-5).
//  - prep ~10us, global_reduce ~5us.
// Session ledger: 232.4 -> 218.2us (-6.1%). Wins: XCD-aware locality remap
// (-7% qkv), 64x128 wave-tile intensity (-2.5%), band+gp fusion. Flat or
// negative: 10 schedule/phase/occupancy variants (all counter-read).
// NOT at roofline (MfmaUtil ~25%) — structure wall; next step would be a
// different decomposition (cooperative qkv+band fusion keeping q/k/vT in
// L3), out of budget for this session.

#define DEVI __device__ __forceinline__
typedef _Float16 f16;
typedef _Float16 h4 __attribute__((ext_vector_type(4)));
typedef _Float16 f16x8 __attribute__((ext_vector_type(8)));
typedef __attribute__((ext_vector_type(4))) float float4v;

DEVI float4v mfma16(f16x8 a, f16x8 b, float4v c) {
    return __builtin_amdgcn_mfma_f32_16x16x32_f16(a, b, c, 0, 0, 0);
}

DEVI void gl_lds16(const f16* g, f16* l) {
    __builtin_amdgcn_global_load_lds(
        (const __attribute__((address_space(1))) unsigned int*)g,
        (__attribute__((address_space(3))) unsigned int*)l, 16, 0, 0);
}

// ---------------------------------------------------------------------------
// prep: blocks [0,6144) = xcast (fp32->f16, 8192*768); blocks [6144,7008) =
// weight transpose Wt[i*768+n][k] = (f16) W_i[k][n].
// ---------------------------------------------------------------------------
__global__ __launch_bounds__(256) void prep(
    const float* __restrict__ x,
    const float* __restrict__ w0, const float* __restrict__ w1,
    const float* __restrict__ w2, const float* __restrict__ w3,
    const float* __restrict__ w4, const float* __restrict__ w5,
    f16* __restrict__ xh, f16* __restrict__ wt) {
    __shared__ float tile[64][65];
    int bid = blockIdx.x;
    if (bid < 6144) {
        int i = (bid * 256 + threadIdx.x) * 4;
        float4 v = *(const float4*)&x[i];
        h4 o = {(f16)v.x, (f16)v.y, (f16)v.z, (f16)v.w};
        *(h4*)&xh[i] = o;
    } else {
        int t = bid - 6144;
        int i = t / 144, rem = t - i * 144;
        int n0 = (rem % 12) * 64, k0 = (rem / 12) * 64;
        const float* W = (i == 0) ? w0 : (i == 1) ? w1 : (i == 2) ? w2
                       : (i == 3) ? w3 : (i == 4) ? w4 : w5;
        int tx = threadIdx.x & 63, ty = threadIdx.x >> 6;
#pragma unroll
        for (int yy = 0; yy < 64; yy += 4)
            tile[yy + ty][tx] = W[(size_t)(k0 + yy + ty) * 768 + n0 + tx];
        __syncthreads();
#pragma unroll
        for (int yy = 0; yy < 64; yy += 4)
            wt[(size_t)(i * 768 + n0 + yy + ty) * 768 + k0 + tx] = (f16)tile[tx][yy + ty];
    }
}

// ---------------------------------------------------------------------------
// qkv_mfma11 (R19, proven best): 128x256 block tile, 64x128 wave tile,
// ring-3, counted vmcnt, XCD remap, XOR swizzle, setprio.
// ---------------------------------------------------------------------------
__global__ __launch_bounds__(256, 2) void qkv_mfma11(
    const f16* __restrict__ Xh, const f16* __restrict__ Wt,
    const float* __restrict__ b0, const float* __restrict__ b1,
    const float* __restrict__ b2, const float* __restrict__ b3,
    const float* __restrict__ b4, const float* __restrict__ b5,
    f16* __restrict__ q, f16* __restrict__ k, f16* __restrict__ vT,
    f16* __restrict__ qg, f16* __restrict__ kg, f16* __restrict__ vgT) {
    __shared__ __align__(16) char smem[73728];   // ring-3 x (8KB A + 16KB B)
    f16* As = (f16*)smem;                        // 3 slots x 4096 f16, [128][32]
    f16* Bs = (f16*)(smem + 24576);              // 3 slots x 8192 f16, [256][32]
    f16* Cl = (f16*)smem;                        // aliased epilogue buffer

    int tid = threadIdx.x, lane = tid & 63, wid = tid >> 6;
    int quad = lane >> 4, l15 = lane & 15;

    int L = blockIdx.x + (blockIdx.y << 6);
    int xcd = L & 7, W = L >> 3;
    int mt = xcd * 8 + (W & 7);
    int yy = W >> 3;                             // 0..17
    int m0 = mt * 128;
    int grp = yy / 3;
    if (grp == 3 && (m0 & 4095) != 0) return;    // qg: only s<32 tiles matter
    int nb = (yy - grp * 3) * 256;               // 0 / 256 / 512
    int wm = (wid >> 1) * 64;
    int wn = (wid & 1) * 128;
    const f16* arow0 = Xh + (size_t)m0 * 768;
    const f16* brow0 = Wt + (size_t)(grp * 768 + nb) * 768;

    float4v acc[4][8];
#pragma unroll
    for (int i = 0; i < 4; ++i)
#pragma unroll
        for (int j = 0; j < 8; ++j) acc[i][j] = (float4v){0.f, 0.f, 0.f, 0.f};

    int r0 = tid >> 2;
    int o0 = (((tid & 3) ^ ((r0 >> 1) & 3)) << 3);
    int sw8 = ((quad ^ ((l15 >> 1) & 3)) << 3);

    auto STAGE_T = [&](int kt, int buf) {
        int k0 = kt << 5;
        const f16* ag = &arow0[(size_t)r0 * 768 + k0 + o0];
        const f16* bg = &brow0[(size_t)r0 * 768 + k0 + o0];
        f16* al = As + buf * 4096 + wid * 512;
        f16* bl = Bs + buf * 8192 + wid * 512;
        gl_lds16(ag, al);
        gl_lds16(ag + (size_t)64 * 768, al + 2048);
        gl_lds16(bg, bl);
        gl_lds16(bg + (size_t)64 * 768, bl + 2048);
        gl_lds16(bg + (size_t)128 * 768, bl + 4096);
        gl_lds16(bg + (size_t)192 * 768, bl + 6144);
    };

    auto COMPUTE_T = [&](int t) {
        const f16* Ab = As + (t % 3) * 4096;
        const f16* Bb = Bs + (t % 3) * 8192;
        f16x8 af[4], bf[8];
#pragma unroll
        for (int i = 0; i < 4; ++i)
            af[i] = *(const f16x8*)&Ab[(wm + i * 16 + l15) * 32 + sw8];
#pragma unroll
        for (int j = 0; j < 8; ++j)
            bf[j] = *(const f16x8*)&Bb[(wn + j * 16 + l15) * 32 + sw8];
        __builtin_amdgcn_s_setprio(1);
#pragma unroll
        for (int i = 0; i < 4; ++i)
#pragma unroll
            for (int j = 0; j < 8; ++j)
                acc[i][j] = mfma16(af[i], bf[j], acc[i][j]);
        __builtin_amdgcn_s_setprio(0);
    };

    STAGE_T(0, 0);
    STAGE_T(1, 1);
#pragma unroll
    for (int t = 0; t < 24; ++t) {
        if (t < 23) {
            asm volatile("s_waitcnt vmcnt(6)" ::: "memory");
        } else {
            asm volatile("s_waitcnt vmcnt(0)" ::: "memory");
        }
        __builtin_amdgcn_s_barrier();
        __builtin_amdgcn_sched_barrier(0);
        if (t + 2 <= 23) STAGE_T(t + 2, (t + 2) % 3);
        COMPUTE_T(t);
    }
    __syncthreads();

    const float* Bsel = (grp == 0) ? b0 : (grp == 1) ? b1 : (grp == 2) ? b2
                      : (grp == 3) ? b3 : (grp == 4) ? b4 : b5;
    int b = m0 >> 12;
    bool tr = (grp == 2 || grp == 5);

    if (tr) {
        constexpr int CLD2 = 136;
#pragma unroll
        for (int j = 0; j < 8; ++j) {
            float bias = Bsel[nb + wn + j * 16 + l15];
#pragma unroll
            for (int i = 0; i < 4; ++i) {
                float4v a = acc[i][j];
                h4 pk = {(f16)(a[0] + bias), (f16)(a[1] + bias),
                         (f16)(a[2] + bias), (f16)(a[3] + bias)};
                *(h4*)&Cl[(wn + j * 16 + l15) * CLD2 + wm + i * 16 + quad * 4] = pk;
            }
        }
        __syncthreads();
        f16* base = (grp == 2) ? vT : vgT;
        int c = tid;
        int ncol = nb + c, h = ncol >> 6, hd = ncol & 63;
        f16* dst = &base[((size_t)((b * 12 + h) * 64 + hd)) * 4096 + (m0 & 4095)];
        const f16* src = &Cl[c * CLD2];
#pragma unroll
        for (int ii = 0; ii < 16; ++ii)
            *(f16x8*)&dst[ii * 8] = *(const f16x8*)&src[ii * 8];
    } else {
        constexpr int CLD = 264;
        float scale = (grp == 0 || grp == 3) ? 0.125f : 1.0f;
#pragma unroll
        for (int j = 0; j < 8; ++j) {
            float bias = Bsel[nb + wn + j * 16 + l15];
#pragma unroll
            for (int i = 0; i < 4; ++i) {
                float4v a = acc[i][j];
#pragma unroll
                for (int r = 0; r < 4; ++r)
                    Cl[(wm + i * 16 + quad * 4 + r) * CLD + wn + j * 16 + l15] =
                        (f16)((a[r] + bias) * scale);
            }
        }
        __syncthreads();
        int row = tid & 127, half = tid >> 7;
        int s = (m0 & 4095) + row;
        const f16* src = &Cl[row * CLD + half * 128];
        if (grp == 3) {
            if (s < 32) {
#pragma unroll
                for (int ii = 0; ii < 16; ++ii) {
                    int h = (nb >> 6) + (half << 1) + (ii >> 3), hd = (ii & 7) * 8;
                    *(f16x8*)&qg[((size_t)((b * 12 + h) * 32 + s)) * 64 + hd] =
                        *(const f16x8*)&src[ii * 8];
                }
            }
        } else {
            f16* baseb = (grp == 0) ? q : (grp == 1) ? k : kg;
#pragma unroll
            for (int ii = 0; ii < 16; ++ii) {
                int h = (nb >> 6) + (half << 1) + (ii >> 3), hd = (ii & 7) * 8;
                *(f16x8*)&baseb[((size_t)((b * 12 + h) * 4096 + s)) * 64 + hd] =
                    *(const f16x8*)&src[ii * 8];
            }
        }
    }
}

// ---------------------------------------------------------------------------
// band_global: blocks [0,768) = band_mfma5 body (R11 mapping, proven);
// blocks [768,960) = global_part body (proven). LDS unioned: 51712 B
// (band 46080, gp 51712) -> 3 blocks/CU.
// ---------------------------------------------------------------------------
__global__ __launch_bounds__(256, 3) void band_global(
    const f16* __restrict__ q, const f16* __restrict__ k, const f16* __restrict__ vT,
    const f16* __restrict__ qg, const f16* __restrict__ kg, const f16* __restrict__ vgT,
    float* __restrict__ out, float* __restrict__ Opart, float* __restrict__ Lpart) {
    __shared__ __align__(16) char smem[51712];
    int tid = threadIdx.x, lane = tid & 63, wid = tid >> 6;
    int quad = lane >> 4, l15 = lane & 15;

    if (blockIdx.x < 768) {
        // ----- band body (R11 proven, linear c mapping) -----
        constexpr int LDK = 72, LDV = 136, LDP = 40;
        f16* Kt = (f16*)smem;                          // 128*72*2   = 18432
        f16* Vt = (f16*)(smem + 18432);                // 64*136*2   = 17408
        f16* PW = (f16*)(smem + 35840) + wid * 32 * LDP;  // 4*32*40*2 = 10240
        int c = blockIdx.x & 31, h = (blockIdx.x >> 5) % 12, b = blockIdx.x / 384;
        const f16* qsl = q + (size_t)(b * 12 + h) * 4096 * 64;
        const f16* ksl = k + (size_t)(b * 12 + h) * 4096 * 64;
        const f16* vsl = vT + (size_t)(b * 12 + h) * 64 * 4096;
        int q0 = c * 128;
        int pq0 = q0 + wid * 32;

        f16x8 qf[2][2];
#pragma unroll
        for (int qg2 = 0; qg2 < 2; ++qg2)
#pragma unroll
            for (int ks = 0; ks < 2; ++ks)
                qf[qg2][ks] = *(const f16x8*)&qsl[(size_t)(pq0 + qg2 * 16 + l15) * 64 +
                                                  ks * 32 + quad * 8];

        float4v Ot[4][2];
#pragma unroll
        for (int dt = 0; dt < 4; ++dt)
#pragma unroll
            for (int qg2 = 0; qg2 < 2; ++qg2) Ot[dt][qg2] = (float4v){0.f, 0.f, 0.f, 0.f};
        float lacc[2] = {0.f, 0.f};

        {
#pragma unroll
            for (int jt = 0; jt < 2; ++jt) {
                f16x8 kf0 = *(const f16x8*)&ksl[(size_t)(jt * 16 + l15) * 64 + quad * 8];
                f16x8 kf1 = *(const f16x8*)&ksl[(size_t)(jt * 16 + l15) * 64 + 32 + quad * 8];
#pragma unroll
                for (int qg2 = 0; qg2 < 2; ++qg2) {
                    float4v sacc = (float4v){0.f, 0.f, 0.f, 0.f};
                    sacc = mfma16(kf0, qf[qg2][0], sacc);
                    sacc = mfma16(kf1, qf[qg2][1], sacc);
                    float p0 = __expf(sacc[0]), p1 = __expf(sacc[1]);
                    float p2 = __expf(sacc[2]), p3 = __expf(sacc[3]);
                    lacc[qg2] += (p0 + p1) + (p2 + p3);
                    h4 pk = {(f16)p0, (f16)p1, (f16)p2, (f16)p3};
                    *(h4*)&PW[(qg2 * 16 + l15) * LDP + jt * 16 + quad * 4] = pk;
                }
            }
            f16x8 pf0 = *(const f16x8*)&PW[l15 * LDP + quad * 8];
            f16x8 pf1 = *(const f16x8*)&PW[(16 + l15) * LDP + quad * 8];
#pragma unroll
            for (int dt = 0; dt < 4; ++dt) {
                f16x8 vf = *(const f16x8*)&vsl[(size_t)(dt * 16 + l15) * 4096 + quad * 8];
                Ot[dt][0] = mfma16(vf, pf0, Ot[dt][0]);
                Ot[dt][1] = mfma16(vf, pf1, Ot[dt][1]);
            }
        }

        for (int r = 0; r < 5; ++r) {
            int kb = q0 - 256 + r * 128;
            if (kb < 0 || kb >= 4096) continue;
            __syncthreads();
            {
                int kr = tid >> 1, ko = (tid & 1) * 32;
                const f16* ks2 = &ksl[(size_t)(kb + kr) * 64 + ko];
                f16* kd = &Kt[kr * LDK + ko];
#pragma unroll
                for (int i = 0; i < 4; ++i) *(f16x8*)&kd[i * 8] = *(const f16x8*)&ks2[i * 8];
                int vr = tid >> 2, vo = (tid & 3) * 32;
                const f16* vs2 = &vsl[(size_t)vr * 4096 + kb + vo];
                f16* vd = &Vt[vr * LDV + vo];
#pragma unroll
                for (int i = 0; i < 4; ++i) *(f16x8*)&vd[i * 8] = *(const f16x8*)&vs2[i * 8];
            }
            __syncthreads();

            if (kb + 127 < pq0 - 256 || kb > pq0 + 287) continue;

#pragma unroll
            for (int tt = 0; tt < 2; ++tt) {
                int tb = kb + tt * 64;
                if (tb + 63 < pq0 - 256 || tb > pq0 + 287) continue;
#pragma unroll
                for (int hf = 0; hf < 2; ++hf) {
#pragma unroll
                    for (int jt = 0; jt < 2; ++jt) {
                        int jl = tt * 64 + hf * 32 + jt * 16;
                        f16x8 kf0 = *(const f16x8*)&Kt[(jl + l15) * LDK + quad * 8];
                        f16x8 kf1 = *(const f16x8*)&Kt[(jl + l15) * LDK + 32 + quad * 8];
                        int j0 = kb + jl;
#pragma unroll
                        for (int qg2 = 0; qg2 < 2; ++qg2) {
                            int qlo = pq0 + qg2 * 16;
                            h4 pk = {(f16)0.f, (f16)0.f, (f16)0.f, (f16)0.f};
                            bool dead = (j0 < qlo - 271) || (j0 > qlo + 271);
                            if (!dead) {
                                float4v sacc = (float4v){0.f, 0.f, 0.f, 0.f};
                                sacc = mfma16(kf0, qf[qg2][0], sacc);
                                sacc = mfma16(kf1, qf[qg2][1], sacc);
                                float p[4];
                                bool full = (j0 >= qlo - 241) && (j0 <= qlo + 241);
                                if (full) {
#pragma unroll
                                    for (int rr = 0; rr < 4; ++rr) p[rr] = __expf(sacc[rr]);
                                } else {
#pragma unroll
                                    for (int rr = 0; rr < 4; ++rr) {
                                        int d = (j0 + quad * 4 + rr) - (qlo + l15);
                                        p[rr] = ((unsigned)(d + 256) <= 512u) ? __expf(sacc[rr]) : 0.f;
                                    }
                                }
                                lacc[qg2] += (p[0] + p[1]) + (p[2] + p[3]);
                                pk = (h4){(f16)p[0], (f16)p[1], (f16)p[2], (f16)p[3]};
                            }
                            *(h4*)&PW[(qg2 * 16 + l15) * LDP + jt * 16 + quad * 4] = pk;
                        }
                    }
                    f16x8 pf0 = *(const f16x8*)&PW[l15 * LDP + quad * 8];
                    f16x8 pf1 = *(const f16x8*)&PW[(16 + l15) * LDP + quad * 8];
#pragma unroll
                    for (int dt = 0; dt < 4; ++dt) {
                        f16x8 vf = *(const f16x8*)&Vt[(dt * 16 + l15) * LDV +
                                                      tt * 64 + hf * 32 + quad * 8];
                        Ot[dt][0] = mfma16(vf, pf0, Ot[dt][0]);
                        Ot[dt][1] = mfma16(vf, pf1, Ot[dt][1]);
                    }
                }
            }
        }

#pragma unroll
        for (int qg2 = 0; qg2 < 2; ++qg2) {
            float lsum = lacc[qg2];
            lsum += __shfl_xor(lsum, 16);
            lsum += __shfl_xor(lsum, 32);
            float inv = 1.f / lsum;
            size_t orow = (size_t)(b * 4096 + pq0 + qg2 * 16 + l15) * 768 + h * 64;
#pragma unroll
            for (int dt = 0; dt < 4; ++dt) {
                float4 o4 = {Ot[dt][qg2][0] * inv, Ot[dt][qg2][1] * inv,
                             Ot[dt][qg2][2] * inv, Ot[dt][qg2][3] * inv};
                *(float4*)&out[orow + dt * 16 + quad * 4] = o4;
            }
        }
    } else {
        // ----- global_part body (proven) -----
        constexpr int LDP = 72;
        f16* PW = (f16*)smem + wid * 32 * LDP;         // 4*32*72*2 = 18432
        float* Osh = (float*)(smem + 18432);           // 4*2048*4  = 32768
        float* Lsh = (float*)(smem + 18432 + 32768);   // 4*32*4    = 512
        int bid = blockIdx.x - 768;
        int sl = bid & 7, bh = bid >> 3;
        const f16* qsl = qg + (size_t)bh * 32 * 64;
        const f16* ksl = kg + (size_t)bh * 4096 * 64;
        const f16* vsl = vgT + (size_t)bh * 64 * 4096;
        int kbase = sl * 512 + wid * 128;

        f16x8 qf[2][2];
#pragma unroll
        for (int g = 0; g < 2; ++g)
#pragma unroll
            for (int ks = 0; ks < 2; ++ks)
                qf[g][ks] = *(const f16x8*)&qsl[(size_t)(g * 16 + l15) * 64 + ks * 32 + quad * 8];

        float4v Ot[4][2];
#pragma unroll
        for (int dt = 0; dt < 4; ++dt)
#pragma unroll
            for (int g = 0; g < 2; ++g) Ot[dt][g] = (float4v){0.f, 0.f, 0.f, 0.f};
        float lacc[2] = {0.f, 0.f};

#pragma unroll
        for (int hf = 0; hf < 2; ++hf) {
            int kh0 = kbase + hf * 64;
#pragma unroll
            for (int kt = 0; kt < 4; ++kt) {
                int jb = kh0 + kt * 16;
                f16x8 kf0 = *(const f16x8*)&ksl[(size_t)(jb + l15) * 64 + quad * 8];
                f16x8 kf1 = *(const f16x8*)&ksl[(size_t)(jb + l15) * 64 + 32 + quad * 8];
#pragma unroll
                for (int g = 0; g < 2; ++g) {
                    float4v sacc = (float4v){0.f, 0.f, 0.f, 0.f};
                    sacc = mfma16(kf0, qf[g][0], sacc);
                    sacc = mfma16(kf1, qf[g][1], sacc);
                    float p0 = __expf(sacc[0]), p1 = __expf(sacc[1]);
                    float p2 = __expf(sacc[2]), p3 = __expf(sacc[3]);
                    lacc[g] += (p0 + p1) + (p2 + p3);
                    h4 pk = {(f16)p0, (f16)p1, (f16)p2, (f16)p3};
                    *(h4*)&PW[(g * 16 + l15) * LDP + kt * 16 + quad * 4] = pk;
                }
            }
#pragma unroll
            for (int kh = 0; kh < 2; ++kh) {
                f16x8 pf0 = *(const f16x8*)&PW[l15 * LDP + kh * 32 + quad * 8];
                f16x8 pf1 = *(const f16x8*)&PW[(16 + l15) * LDP + kh * 32 + quad * 8];
#pragma unroll
                for (int dt = 0; dt < 4; ++dt) {
                    f16x8 vf = *(const f16x8*)&vsl[(size_t)(dt * 16 + l15) * 4096 +
                                                   kh0 + kh * 32 + quad * 8];
                    Ot[dt][0] = mfma16(vf, pf0, Ot[dt][0]);
                    Ot[dt][1] = mfma16(vf, pf1, Ot[dt][1]);
                }
            }
        }

#pragma unroll
        for (int g = 0; g < 2; ++g) {
            lacc[g] += __shfl_xor(lacc[g], 16);
            lacc[g] += __shfl_xor(lacc[g], 32);
        }
        if (quad == 0) { Lsh[wid * 32 + l15] = lacc[0]; Lsh[wid * 32 + 16 + l15] = lacc[1]; }
#pragma unroll
        for (int dt = 0; dt < 4; ++dt)
#pragma unroll
            for (int g = 0; g < 2; ++g)
#pragma unroll
                for (int r = 0; r < 4; ++r)
                    Osh[wid * 2048 + (dt * 16 + quad * 4 + r) * 32 + g * 16 + l15] = Ot[dt][g][r];
        __syncthreads();
#pragma unroll
        for (int i = 0; i < 8; ++i) {
            int idx = tid + i * 256;
            int d = idx & 63, qq = idx >> 6;
            float v = Osh[0 * 2048 + d * 32 + qq] + Osh[1 * 2048 + d * 32 + qq] +
                      Osh[2 * 2048 + d * 32 + qq] + Osh[3 * 2048 + d * 32 + qq];
            Opart[(size_t)bid * 2048 + idx] = v;
        }
        if (tid < 32)
            Lpart[bid * 32 + tid] = Lsh[0 * 32 + tid] + Lsh[1 * 32 + tid] +
                                    Lsh[2 * 32 + tid] + Lsh[3 * 32 + tid];
    }
}

__global__ __launch_bounds__(256) void global_reduce(
    const float* __restrict__ Opart, const float* __restrict__ Lpart,
    float* __restrict__ out) {
    __shared__ float Ls[32];
    int tid = threadIdx.x, bh = blockIdx.x;
    int b = bh / 12, h = bh % 12;
    if (tid < 32) {
        float s = 0.f;
#pragma unroll
        for (int sl = 0; sl < 8; ++sl) s += Lpart[(bh * 8 + sl) * 32 + tid];
        Ls[tid] = s;
    }
    __syncthreads();
#pragma unroll
    for (int i = 0; i < 8; ++i) {
        int idx = tid + i * 256;
        int d = idx & 63, qq = idx >> 6;
        float o = 0.f;
#pragma unroll
        for (int sl = 0; sl < 8; ++sl) o += Opart[(size_t)(bh * 8 + sl) * 2048 + idx];
        out[(size_t)(b * 4096 + qq) * 768 + h * 64 + d] = o / Ls[qq];
    }
}

// ---------------------------------------------------------------------------
extern "C" void kernel_launch(void* const* d_in, const int* in_sizes, int n_in,
                              void* d_out, int out_size, void* d_ws, size_t ws_size,
                              hipStream_t stream) {
    const float* hs = (const float*)d_in[0];
    float* outp = (float*)d_out;

    char* p = (char*)d_ws;
    const size_t SLAB = (size_t)2 * 12 * 4096 * 64 * sizeof(f16);   // 12,582,912 B
    f16* qb   = (f16*)(p + 0 * SLAB);
    f16* kb   = (f16*)(p + 1 * SLAB);
    f16* vtb  = (f16*)(p + 2 * SLAB);   // [bh][d][s]
    f16* kgb  = (f16*)(p + 3 * SLAB);
    f16* vgtb = (f16*)(p + 4 * SLAB);   // [bh][d][s]
    f16* qgb  = (f16*)(p + 5 * SLAB);
    char* p2  = p + 5 * SLAB + 196608;
    f16* xh   = (f16*)p2;
    f16* wt   = (f16*)(p2 + SLAB);
    char* p3  = p2 + SLAB + 7077888;
    float* Opart = (float*)p3;
    float* Lpart = (float*)(p3 + 1572864);

    prep<<<7008, 256, 0, stream>>>(
        hs,
        (const float*)d_in[1], (const float*)d_in[3], (const float*)d_in[5],
        (const float*)d_in[7], (const float*)d_in[9], (const float*)d_in[11],
        xh, wt);
    qkv_mfma11<<<dim3(64, 18), 256, 0, stream>>>(
        xh, wt,
        (const float*)d_in[2], (const float*)d_in[4], (const float*)d_in[6],
        (const float*)d_in[8], (const float*)d_in[10], (const float*)d_in[12],
        qb, kb, vtb, qgb, kgb, vgtb);
    band_global<<<960, 256, 0, stream>>>(
        qb, kb, vtb, qgb, kgb, vgtb, outp, Opart, Lpart);
    global_reduce<<<24, 256, 0, stream>>>(Opart, Lpart, outp);
}